// Round 4
// baseline (3064.709 us; speedup 1.0000x reference)
//
#include <hip/hip_runtime.h>

#define NN 5000
#define EE 120000

typedef __bf16 bf16_t;
typedef __bf16 bf16x8 __attribute__((ext_vector_type(8)));
typedef __bf16 bf16x4 __attribute__((ext_vector_type(4)));
typedef float f32x4 __attribute__((ext_vector_type(4)));

// W^T offsets (elements) inside ws
#define OFF_EEW2T 0
#define OFF_ECW1T 65536
#define OFF_ECW2T 196608
#define OFF_FW1T  262144
#define OFF_FW2T  524288
#define OFF_LN1T  786432
#define OFF_LN2T  1048576
#define OFF_GW1T  1310720
#define OFF_GW2T  1441792
#define WT_ELEMS  1474560

// ws byte offsets
#define WSOFF_H32   2949120
#define WSOFF_H16   8069120
#define WSOFF_EATTR 10629120
#define WS_NEED_BIG 72069120ull

// XOR-swizzled [rows x 256] bf16 tile: 16B chunks permuted by row, conflict-free
__device__ __forceinline__ int swz(int r, int c) {
  return r * 256 + ((((c >> 3) ^ (r & 7)) << 3) | (c & 7));
}

__device__ __forceinline__ float silu_f(float x) { return x / (1.f + __expf(-x)); }
__device__ __forceinline__ float ssp_f(float x) {
  return (x > 20.f) ? (x - 0.6931472f) : (log1pf(__expf(x)) - 0.6931472f);
}

__device__ __forceinline__ bf16x8 zero8() {
  bf16x8 v;
#pragma unroll
  for (int q = 0; q < 8; ++q) v[q] = (__bf16)0.f;
  return v;
}

template<int RT, int NT>
__device__ __forceinline__ void zacc(f32x4 (&acc)[RT][NT]) {
#pragma unroll
  for (int i = 0; i < RT; ++i)
#pragma unroll
    for (int j = 0; j < NT; ++j) {
      f32x4 z = {0.f, 0.f, 0.f, 0.f};
      acc[i][j] = z;
    }
}

// A: LDS swizzled tile, rows rt*16+l15, k chunks ks*32+quad*8
// WT: global W^T [N, ldK] row-major (bf16); effective B[k][n] = WT[n*ldK + k]
template<int RT, int NT, int KS>
__device__ __forceinline__ void gemm_lds(const bf16_t* __restrict__ A,
                                         const bf16_t* __restrict__ WT, int ldK,
                                         int colBase, f32x4 (&acc)[RT][NT], int lane) {
  const int l15 = lane & 15, quad = lane >> 4;
#pragma unroll
  for (int ks = 0; ks < KS; ++ks) {
    const int kc = ks * 4 + quad;
    bf16x8 a[RT];
#pragma unroll
    for (int rt = 0; rt < RT; ++rt) {
      int r = rt * 16 + l15;
      a[rt] = *(const bf16x8*)(A + r * 256 + ((kc ^ (r & 7)) << 3));
    }
#pragma unroll
    for (int nt = 0; nt < NT; ++nt) {
      const bf16x8 b = *(const bf16x8*)(WT + (size_t)(colBase + nt * 16 + l15) * ldK + kc * 8);
#pragma unroll
      for (int rt = 0; rt < RT; ++rt)
        acc[rt][nt] = __builtin_amdgcn_mfma_f32_16x16x32_bf16(a[rt], b, acc[rt][nt], 0, 0, 0);
    }
  }
}

// Compute edge_attr for a 64-edge chunk starting at eBase (valid rows < valid).
// Result (bf16, swizzled) left in bufB; bufA clobbered. If out!=nullptr also
// writes the d output (f32). All-thread collective; internal __syncthreads.
__device__ void eattr_chunk(
    int eBase, int valid,
    const float* pos, const int* ei, const int* etr, const int* etp,
    const float* eeW1, const float* eeb1, const float* eeb2,
    const float* bemb, const float* ecb1, const float* ecb2,
    const bf16_t* WT, bf16_t* bufA, bf16_t* bufB, float* out) {
  const int tid = threadIdx.x, lane = tid & 63, wave = tid >> 6;
  const int l15 = lane & 15, quad = lane >> 4;
  // phase 1: hidden = silu(d*W1 + b1) -> bufA
  {
    int r = tid >> 2, cb = (tid & 3) << 6;
    bool ok = r < valid;
    int e = eBase + (ok ? r : 0);
    int s = ei[e], dn = ei[EE + e];
    float d0 = pos[dn * 3 + 0] - pos[s * 3 + 0];
    float d1 = pos[dn * 3 + 1] - pos[s * 3 + 1];
    float d2 = pos[dn * 3 + 2] - pos[s * 3 + 2];
    float dd = ok ? sqrtf(d0 * d0 + d1 * d1 + d2 * d2) : 0.f;
    if (ok && out && (tid & 3) == 0) out[3 * EE + e] = dd;
    for (int cc = 0; cc < 64; ++cc) {
      int c = cb + cc;
      float x = dd * eeW1[c] + eeb1[c];
      bufA[swz(r, c)] = (bf16_t)(ok ? silu_f(x) : 0.f);
    }
  }
  __syncthreads();
  f32x4 acc[4][4];
  // GEMM1: mlp_d = hidden @ eeW2 (bias later)
  zacc(acc);
  gemm_lds<4, 4, 8>(bufA, WT + OFF_EEW2T, 256, wave * 64, acc, lane);
  __syncthreads();
  // gates: attr_r -> bufA, attr_p -> bufB
#pragma unroll
  for (int rt = 0; rt < 4; ++rt)
#pragma unroll
    for (int reg = 0; reg < 4; ++reg) {
      int r = rt * 16 + quad * 4 + reg;
      bool ok = r < valid;
      int e = eBase + (ok ? r : 0);
      int tr = ok ? etr[e] : 0, tp = ok ? etp[e] : 0;
#pragma unroll
      for (int nt = 0; nt < 4; ++nt) {
        int c = wave * 64 + nt * 16 + l15;
        float mlp = acc[rt][nt][reg] + eeb2[c];
        bufA[swz(r, c)] = (bf16_t)(ok ? mlp * bemb[tr * 256 + c] : 0.f);
        bufB[swz(r, c)] = (bf16_t)(ok ? mlp * bemb[tp * 256 + c] : 0.f);
      }
    }
  __syncthreads();
  // GEMM2: s1 = silu(cat(attr_r, attr_p) @ ecW1 + b1)
  zacc(acc);
  gemm_lds<4, 4, 8>(bufA, WT + OFF_ECW1T, 512, wave * 64, acc, lane);
  gemm_lds<4, 4, 8>(bufB, WT + OFF_ECW1T + 256, 512, wave * 64, acc, lane);
  __syncthreads();
#pragma unroll
  for (int rt = 0; rt < 4; ++rt)
#pragma unroll
    for (int reg = 0; reg < 4; ++reg) {
      int r = rt * 16 + quad * 4 + reg;
#pragma unroll
      for (int nt = 0; nt < 4; ++nt) {
        int c = wave * 64 + nt * 16 + l15;
        bufA[swz(r, c)] = (bf16_t)silu_f(acc[rt][nt][reg] + ecb1[c]);
      }
    }
  __syncthreads();
  // GEMM3: edge_attr = s1 @ ecW2 + b2 -> bufB
  zacc(acc);
  gemm_lds<4, 4, 8>(bufA, WT + OFF_ECW2T, 256, wave * 64, acc, lane);
  __syncthreads();
#pragma unroll
  for (int rt = 0; rt < 4; ++rt)
#pragma unroll
    for (int reg = 0; reg < 4; ++reg) {
      int r = rt * 16 + quad * 4 + reg;
#pragma unroll
      for (int nt = 0; nt < 4; ++nt) {
        int c = wave * 64 + nt * 16 + l15;
        bufB[swz(r, c)] = (bf16_t)(acc[rt][nt][reg] + ecb2[c]);
      }
    }
}

// ---------------- weight transpose (f32 -> bf16 W^T) ----------------
__global__ __launch_bounds__(256) void k_transpose(
    const float* eeW2, const float* ecW1, const float* ecW2,
    const float* fW1, const float* fW2, const float* ln1, const float* ln2,
    const float* gW1, const float* gW2, bf16_t* WT) {
  int seg = blockIdx.y;
  const float* src; int K, Nn, off;
  if (seg == 0)       { src = eeW2; K = 256; Nn = 256; off = OFF_EEW2T; }
  else if (seg == 1)  { src = ecW1; K = 512; Nn = 256; off = OFF_ECW1T; }
  else if (seg == 2)  { src = ecW2; K = 256; Nn = 256; off = OFF_ECW2T; }
  else if (seg <= 6)  { int l = seg - 3;  src = fW1 + l * 65536; K = 256; Nn = 256; off = OFF_FW1T + l * 65536; }
  else if (seg <= 10) { int l = seg - 7;  src = fW2 + l * 65536; K = 256; Nn = 256; off = OFF_FW2T + l * 65536; }
  else if (seg <= 14) { int l = seg - 11; src = ln1 + l * 65536; K = 256; Nn = 256; off = OFF_LN1T + l * 65536; }
  else if (seg <= 18) { int l = seg - 15; src = ln2 + l * 65536; K = 256; Nn = 256; off = OFF_LN2T + l * 65536; }
  else if (seg == 19) { src = gW1; K = 512; Nn = 256; off = OFF_GW1T; }
  else                { src = gW2; K = 256; Nn = 128; off = OFF_GW2T; }
  int idx = blockIdx.x * 256 + threadIdx.x;
  if (idx >= K * Nn) return;
  int sh = (K == 512) ? 9 : 8;
  int k = idx & (K - 1), n = idx >> sh;
  WT[off + idx] = (bf16_t)src[k * Nn + n];
}

// ---------------- node embedding ----------------
__global__ __launch_bounds__(128) void k_node(
    const float* r_feat, const float* p_feat, const float* emb, const float* Wf,
    const int* atype, float* h32, bf16_t* h16) {
  __shared__ float rf[27], pf[27];
  int n = blockIdx.x, t = threadIdx.x;
  if (t < 27) { rf[t] = r_feat[n * 27 + t]; pf[t] = p_feat[n * 27 + t]; }
  __syncthreads();
  float fr = 0.f, fp = 0.f;
#pragma unroll
  for (int k = 0; k < 27; ++k) {
    float w = Wf[k * 128 + t];
    fr += rf[k] * w; fp += pf[k] * w;
  }
  int at = atype[n];
  float z0 = emb[at * 128 + t] + fr;
  float z1 = fp - fr;
  size_t base = (size_t)n * 256;
  h32[base + t] = z0;       h32[base + 128 + t] = z1;
  h16[base + t] = (bf16_t)z0; h16[base + 128 + t] = (bf16_t)z1;
}

// ---------------- fused edge embedding (big-ws path only) ----------------
__global__ __launch_bounds__(256) void k_edge_attr(
    const float* pos, const int* ei, const int* etr, const int* etp,
    const float* eeW1, const float* eeb1, const float* eeb2,
    const float* bemb, const float* ecb1, const float* ecb2,
    const bf16_t* WT, bf16_t* eattr, float* out) {
  __shared__ bf16_t buf0[64 * 256];
  __shared__ bf16_t buf1[64 * 256];
  const int eBase = blockIdx.x * 64;
  eattr_chunk(eBase, 64, pos, ei, etr, etp, eeW1, eeb1, eeb2, bemb, ecb1, ecb2,
              WT, buf0, buf1, out);
  __syncthreads();
  const int tid = threadIdx.x;
  for (int i = tid; i < 64 * 32; i += 256) {
    int r = i >> 5, kc = i & 31;
    *(bf16x8*)(eattr + (size_t)(eBase + r) * 256 + kc * 8) =
        *(const bf16x8*)(buf1 + r * 256 + ((kc ^ (r & 7)) << 3));
  }
}

// ---------------- one CFConv interaction layer; block = one molecule ----------------
__global__ __launch_bounds__(256) void k_conv(
    const bf16_t* eattr, const int* ei,
    const bf16_t* lin1T, const bf16_t* fW1T, const bf16_t* fW2T, const bf16_t* lin2T,
    const float* fb1, const float* fb2, const float* lin2b,
    float* h32, bf16_t* h16,
    int recomp,
    const float* pos, const int* etr, const int* etp,
    const float* eeW1, const float* eeb1, const float* eeb2,
    const float* bemb, const float* ecb1, const float* ecb2, const bf16_t* WT) {
  __shared__ bf16_t buf0[64 * 256];
  __shared__ bf16_t buf1[64 * 256];
  __shared__ bf16_t hl[32 * 264];
  __shared__ float agg[25 * 260];
  __shared__ int sdl[64], ddl[64];
  const int tid = threadIdx.x, lane = tid & 63, wave = tid >> 6;
  const int l15 = lane & 15, quad = lane >> 4;
  const int mol = blockIdx.x, molN = mol * 25, molE = mol * 600;

  // stage own h rows (pad to 32) + zero agg
  for (int i = tid; i < 32 * 32; i += 256) {
    int r = i >> 5, kc = i & 31;
    bf16x8 v = (r < 25) ? *(const bf16x8*)(h16 + (size_t)(molN + r) * 256 + kc * 8) : zero8();
    *(bf16x8*)(buf0 + r * 256 + ((kc ^ (r & 7)) << 3)) = v;
  }
  for (int i = tid; i < 25 * 260; i += 256) agg[i] = 0.f;
  __syncthreads();
  // hl = h @ lin1 (no bias)
  {
    f32x4 acc[2][4]; zacc(acc);
    gemm_lds<2, 4, 8>(buf0, lin1T, 256, wave * 64, acc, lane);
#pragma unroll
    for (int rt = 0; rt < 2; ++rt)
#pragma unroll
      for (int reg = 0; reg < 4; ++reg) {
        int r = rt * 16 + quad * 4 + reg;
#pragma unroll
        for (int nt = 0; nt < 4; ++nt) {
          int c = wave * 64 + nt * 16 + l15;
          hl[r * 264 + c] = (bf16_t)acc[rt][nt][reg];
        }
      }
  }
  // chunked edge loop
  for (int base = 0; base < 600; base += 64) {
    int valid = (600 - base < 64) ? (600 - base) : 64;
    __syncthreads();
    if (tid < 64) {
      if (tid < valid) {
        int e = molE + base + tid;
        sdl[tid] = ei[e] - molN;
        ddl[tid] = ei[EE + e] - molN;
      } else ddl[tid] = -1;
    }
    if (recomp) {
      eattr_chunk(molE + base, valid, pos, ei, etr, etp, eeW1, eeb1, eeb2,
                  bemb, ecb1, ecb2, WT, buf0, buf1, nullptr);
    } else {
      for (int i = tid; i < 64 * 32; i += 256) {
        int r = i >> 5, kc = i & 31;
        bf16x8 v = (r < valid) ? *(const bf16x8*)(eattr + (size_t)(molE + base + r) * 256 + kc * 8)
                               : zero8();
        *(bf16x8*)(buf1 + r * 256 + ((kc ^ (r & 7)) << 3)) = v;
      }
    }
    __syncthreads();
    // W1: ssp(ea@fW1+b1) -> buf0
    {
      f32x4 acc[4][4]; zacc(acc);
      gemm_lds<4, 4, 8>(buf1, fW1T, 256, wave * 64, acc, lane);
#pragma unroll
      for (int rt = 0; rt < 4; ++rt)
#pragma unroll
        for (int reg = 0; reg < 4; ++reg) {
          int r = rt * 16 + quad * 4 + reg;
#pragma unroll
          for (int nt = 0; nt < 4; ++nt) {
            int c = wave * 64 + nt * 16 + l15;
            buf0[swz(r, c)] = (bf16_t)ssp_f(acc[rt][nt][reg] + fb1[c]);
          }
        }
    }
    __syncthreads();
    // W2 + scatter: agg[dst] += hl[src] * (ssp1@fW2+b2)
    {
      f32x4 acc[4][4]; zacc(acc);
      gemm_lds<4, 4, 8>(buf0, fW2T, 256, wave * 64, acc, lane);
#pragma unroll
      for (int rt = 0; rt < 4; ++rt)
#pragma unroll
        for (int reg = 0; reg < 4; ++reg) {
          int r = rt * 16 + quad * 4 + reg;
          int dL = ddl[r];
          if (dL >= 0) {
            int sL = sdl[r];
#pragma unroll
            for (int nt = 0; nt < 4; ++nt) {
              int c = wave * 64 + nt * 16 + l15;
              float Wv = acc[rt][nt][reg] + fb2[c];
              atomicAdd(&agg[dL * 260 + c], (float)hl[sL * 264 + c] * Wv);
            }
          }
        }
    }
  }
  __syncthreads();
  // h = h + ssp(agg @ lin2 + b)
  for (int i = tid; i < 32 * 256; i += 256) {
    int r = i >> 8, c = i & 255;
    float v = (r < 25) ? agg[r * 260 + c] : 0.f;
    buf0[swz(r, c)] = (bf16_t)v;
  }
  __syncthreads();
  {
    f32x4 acc[2][4]; zacc(acc);
    gemm_lds<2, 4, 8>(buf0, lin2T, 256, wave * 64, acc, lane);
#pragma unroll
    for (int rt = 0; rt < 2; ++rt)
#pragma unroll
      for (int reg = 0; reg < 4; ++reg) {
        int r = rt * 16 + quad * 4 + reg;
        if (r < 25) {
#pragma unroll
          for (int nt = 0; nt < 4; ++nt) {
            int c = wave * 64 + nt * 16 + l15;
            size_t idx = (size_t)(molN + r) * 256 + c;
            float hn = h32[idx] + ssp_f(acc[rt][nt][reg] + lin2b[c]);
            h32[idx] = hn;
            h16[idx] = (bf16_t)hn;
          }
        }
      }
  }
}

// ---------------- output head ----------------
__global__ __launch_bounds__(256) void k_head(
    const float* h32, const bf16_t* eattr, const int* ei,
    const float* gb1, const float* gb2, const float* gW3, const float* gb3,
    const bf16_t* WT, float* out,
    int recomp,
    const float* pos, const int* etr, const int* etp,
    const float* eeW1, const float* eeb1, const float* eeb2,
    const float* bemb, const float* ecb1, const float* ecb2) {
  __shared__ bf16_t buf0[64 * 256];
  __shared__ bf16_t buf1[64 * 256];
  const int tid = threadIdx.x, lane = tid & 63, wave = tid >> 6;
  const int l15 = lane & 15, quad = lane >> 4;
  const int eBase = blockIdx.x * 64;

  if (recomp) {
    eattr_chunk(eBase, 64, pos, ei, etr, etp, eeW1, eeb1, eeb2, bemb, ecb1, ecb2,
                WT, buf0, buf1, out);
  } else {
    for (int i = tid; i < 64 * 32; i += 256) {
      int r = i >> 5, kc = i & 31;
      *(bf16x8*)(buf1 + r * 256 + ((kc ^ (r & 7)) << 3)) =
          *(const bf16x8*)(eattr + (size_t)(eBase + r) * 256 + kc * 8);
    }
  }
  // stage h[src]*h[dst] -> buf0
  for (int i = tid; i < 64 * 64; i += 256) {
    int r = i >> 6, c4 = (i & 63) << 2;
    int e = eBase + r, s = ei[e], dn = ei[EE + e];
    const float4 a = *(const float4*)(h32 + (size_t)s * 256 + c4);
    const float4 b = *(const float4*)(h32 + (size_t)dn * 256 + c4);
    bf16x4 v;
    v[0] = (bf16_t)(a.x * b.x); v[1] = (bf16_t)(a.y * b.y);
    v[2] = (bf16_t)(a.z * b.z); v[3] = (bf16_t)(a.w * b.w);
    *(bf16x4*)(buf0 + swz(r, c4)) = v;
  }
  // emit edge_index outputs (f32)
  if (tid < 64) {
    int e = eBase + tid;
    out[EE + e] = (float)ei[e];
    out[2 * EE + e] = (float)ei[EE + e];
  }
  __syncthreads();
  f32x4 acc[4][4]; zacc(acc);
  gemm_lds<4, 4, 8>(buf0, WT + OFF_GW1T, 512, wave * 64, acc, lane);
  gemm_lds<4, 4, 8>(buf1, WT + OFF_GW1T + 256, 512, wave * 64, acc, lane);
  __syncthreads();
#pragma unroll
  for (int rt = 0; rt < 4; ++rt)
#pragma unroll
    for (int reg = 0; reg < 4; ++reg) {
      int r = rt * 16 + quad * 4 + reg;
#pragma unroll
      for (int nt = 0; nt < 4; ++nt) {
        int c = wave * 64 + nt * 16 + l15;
        buf0[swz(r, c)] = (bf16_t)silu_f(acc[rt][nt][reg] + gb1[c]);
      }
    }
  __syncthreads();
  f32x4 acc2[4][2]; zacc(acc2);
  gemm_lds<4, 2, 8>(buf0, WT + OFF_GW2T, 256, wave * 32, acc2, lane);
  __syncthreads();
#pragma unroll
  for (int rt = 0; rt < 4; ++rt)
#pragma unroll
    for (int reg = 0; reg < 4; ++reg) {
      int r = rt * 16 + quad * 4 + reg;
#pragma unroll
      for (int nt = 0; nt < 2; ++nt) {
        int c = wave * 32 + nt * 16 + l15;
        buf1[swz(r, c)] = (bf16_t)silu_f(acc2[rt][nt][reg] + gb2[c]);
      }
    }
  __syncthreads();
  if (tid < 64) {
    float s = gb3[0];
    for (int c = 0; c < 128; ++c)
      s += (float)buf1[swz(tid, c)] * gW3[c];
    out[eBase + tid] = s;
  }
}

extern "C" void kernel_launch(void* const* d_in, const int* in_sizes, int n_in,
                              void* d_out, int out_size, void* d_ws, size_t ws_size,
                              hipStream_t stream) {
  const float* pos   = (const float*)d_in[0];
  const float* rfeat = (const float*)d_in[1];
  const float* pfeat = (const float*)d_in[2];
  const float* emb   = (const float*)d_in[3];
  const float* Wf    = (const float*)d_in[4];
  const float* bemb  = (const float*)d_in[5];
  const float* eeW1  = (const float*)d_in[6];
  const float* eeb1  = (const float*)d_in[7];
  const float* eeW2  = (const float*)d_in[8];
  const float* eeb2  = (const float*)d_in[9];
  const float* ecW1  = (const float*)d_in[10];
  const float* ecb1  = (const float*)d_in[11];
  const float* ecW2  = (const float*)d_in[12];
  const float* ecb2  = (const float*)d_in[13];
  const float* fW1   = (const float*)d_in[14];
  const float* fb1   = (const float*)d_in[15];
  const float* fW2   = (const float*)d_in[16];
  const float* fb2   = (const float*)d_in[17];
  const float* ln1   = (const float*)d_in[18];
  const float* ln2   = (const float*)d_in[19];
  const float* ln2b  = (const float*)d_in[20];
  const float* gW1   = (const float*)d_in[21];
  const float* gb1   = (const float*)d_in[22];
  const float* gW2   = (const float*)d_in[23];
  const float* gb2   = (const float*)d_in[24];
  const float* gW3   = (const float*)d_in[25];
  const float* gb3   = (const float*)d_in[26];
  const int* atype = (const int*)d_in[27];
  const int* ei    = (const int*)d_in[28];
  const int* etr   = (const int*)d_in[29];
  const int* etp   = (const int*)d_in[30];

  float* out = (float*)d_out;
  char* ws = (char*)d_ws;
  bf16_t* WT    = (bf16_t*)(ws);
  float*  h32   = (float*)(ws + WSOFF_H32);
  bf16_t* h16   = (bf16_t*)(ws + WSOFF_H16);
  const bool big = (ws_size >= WS_NEED_BIG);
  bf16_t* eattr = big ? (bf16_t*)(ws + WSOFF_EATTR) : nullptr;
  const int recomp = big ? 0 : 1;

  k_transpose<<<dim3(512, 21), 256, 0, stream>>>(eeW2, ecW1, ecW2, fW1, fW2, ln1, ln2, gW1, gW2, WT);
  k_node<<<NN, 128, 0, stream>>>(rfeat, pfeat, emb, Wf, atype, h32, h16);
  if (big) {
    k_edge_attr<<<EE / 64, 256, 0, stream>>>(pos, ei, etr, etp, eeW1, eeb1, eeb2,
                                             bemb, ecb1, ecb2, WT, eattr, out);
  }
  for (int l = 0; l < 4; ++l) {
    k_conv<<<200, 256, 0, stream>>>(eattr, ei,
                                    WT + OFF_LN1T + l * 65536,
                                    WT + OFF_FW1T + l * 65536,
                                    WT + OFF_FW2T + l * 65536,
                                    WT + OFF_LN2T + l * 65536,
                                    fb1 + l * 256, fb2 + l * 256, ln2b + l * 256,
                                    h32, h16, recomp,
                                    pos, etr, etp, eeW1, eeb1, eeb2, bemb, ecb1, ecb2, WT);
  }
  k_head<<<EE / 64, 256, 0, stream>>>(h32, eattr, ei, gb1, gb2, gW3, gb3, WT, out,
                                      recomp, pos, etr, etp, eeW1, eeb1, eeb2, bemb, ecb1, ecb2);
}

// Round 5
// 1420.528 us; speedup vs baseline: 2.1574x; 2.1574x over previous
//
#include <hip/hip_runtime.h>

#define NN 5000
#define EE 120000

typedef __bf16 bf16_t;
typedef __bf16 bf16x8 __attribute__((ext_vector_type(8)));
typedef float f32x4 __attribute__((ext_vector_type(4)));

// W^T offsets (elements) inside ws
#define OFF_EEW2T 0
#define OFF_ECW1T 65536
#define OFF_ECW2T 196608
#define OFF_FW1T  262144
#define OFF_FW2T  524288
#define OFF_LN1T  786432
#define OFF_LN2T  1048576
#define OFF_GW1T  1310720
#define OFF_GW2T  1441792

// ws byte offsets (total exactly 72,069,120 B — proven available)
#define WSOFF_H16   2949120
#define WSOFF_HL    5509120
#define WSOFF_AGG   8069120
#define WSOFF_EATTR 10629120

// XOR-swizzled [rows x 256] bf16 tile: 16B chunks permuted by row, conflict-free
__device__ __forceinline__ int swz(int r, int c) {
  return r * 256 + ((((c >> 3) ^ (r & 7)) << 3) | (c & 7));
}

__device__ __forceinline__ float silu_f(float x) { return x / (1.f + __expf(-x)); }
__device__ __forceinline__ float ssp_f(float x) {
  return (x > 20.f) ? (x - 0.6931472f) : (log1pf(__expf(x)) - 0.6931472f);
}

__device__ __forceinline__ bf16x8 zero8() {
  bf16x8 v;
#pragma unroll
  for (int q = 0; q < 8; ++q) v[q] = (__bf16)0.f;
  return v;
}

template<int RT, int NT>
__device__ __forceinline__ void zacc(f32x4 (&acc)[RT][NT]) {
#pragma unroll
  for (int i = 0; i < RT; ++i)
#pragma unroll
    for (int j = 0; j < NT; ++j) {
      f32x4 z = {0.f, 0.f, 0.f, 0.f};
      acc[i][j] = z;
    }
}

// A: LDS swizzled tile, rows rt*16+l15, k chunks ks*32+quad*8
// WT: global W^T [N, ldK] row-major (bf16); effective B[k][n] = WT[n*ldK + k]
template<int RT, int NT, int KS>
__device__ __forceinline__ void gemm_lds(const bf16_t* __restrict__ A,
                                         const bf16_t* __restrict__ WT, int ldK,
                                         int colBase, f32x4 (&acc)[RT][NT], int lane) {
  const int l15 = lane & 15, quad = lane >> 4;
#pragma unroll
  for (int ks = 0; ks < KS; ++ks) {
    const int kc = ks * 4 + quad;
    bf16x8 a[RT];
#pragma unroll
    for (int rt = 0; rt < RT; ++rt) {
      int r = rt * 16 + l15;
      a[rt] = *(const bf16x8*)(A + r * 256 + ((kc ^ (r & 7)) << 3));
    }
#pragma unroll
    for (int nt = 0; nt < NT; ++nt) {
      const bf16x8 b = *(const bf16x8*)(WT + (size_t)(colBase + nt * 16 + l15) * ldK + kc * 8);
#pragma unroll
      for (int rt = 0; rt < RT; ++rt)
        acc[rt][nt] = __builtin_amdgcn_mfma_f32_16x16x32_bf16(a[rt], b, acc[rt][nt], 0, 0, 0);
    }
  }
}

// ---------------- weight transpose (f32 -> bf16 W^T) ----------------
__global__ __launch_bounds__(256) void k_transpose(
    const float* eeW2, const float* ecW1, const float* ecW2,
    const float* fW1, const float* fW2, const float* ln1, const float* ln2,
    const float* gW1, const float* gW2, bf16_t* WT) {
  int seg = blockIdx.y;
  const float* src; int K, Nn, off;
  if (seg == 0)       { src = eeW2; K = 256; Nn = 256; off = OFF_EEW2T; }
  else if (seg == 1)  { src = ecW1; K = 512; Nn = 256; off = OFF_ECW1T; }
  else if (seg == 2)  { src = ecW2; K = 256; Nn = 256; off = OFF_ECW2T; }
  else if (seg <= 6)  { int l = seg - 3;  src = fW1 + l * 65536; K = 256; Nn = 256; off = OFF_FW1T + l * 65536; }
  else if (seg <= 10) { int l = seg - 7;  src = fW2 + l * 65536; K = 256; Nn = 256; off = OFF_FW2T + l * 65536; }
  else if (seg <= 14) { int l = seg - 11; src = ln1 + l * 65536; K = 256; Nn = 256; off = OFF_LN1T + l * 65536; }
  else if (seg <= 18) { int l = seg - 15; src = ln2 + l * 65536; K = 256; Nn = 256; off = OFF_LN2T + l * 65536; }
  else if (seg == 19) { src = gW1; K = 512; Nn = 256; off = OFF_GW1T; }
  else                { src = gW2; K = 256; Nn = 128; off = OFF_GW2T; }
  int idx = blockIdx.x * 256 + threadIdx.x;
  if (idx >= K * Nn) return;
  int sh = (K == 512) ? 9 : 8;
  int k = idx & (K - 1), n = idx >> sh;
  WT[off + idx] = (bf16_t)src[k * Nn + n];
}

// ---------------- node embedding ----------------
__global__ __launch_bounds__(128) void k_node(
    const float* r_feat, const float* p_feat, const float* emb, const float* Wf,
    const int* atype, bf16_t* h16) {
  __shared__ float rf[27], pf[27];
  int n = blockIdx.x, t = threadIdx.x;
  if (t < 27) { rf[t] = r_feat[n * 27 + t]; pf[t] = p_feat[n * 27 + t]; }
  __syncthreads();
  float fr = 0.f, fp = 0.f;
#pragma unroll
  for (int k = 0; k < 27; ++k) {
    float w = Wf[k * 128 + t];
    fr += rf[k] * w; fp += pf[k] * w;
  }
  int at = atype[n];
  size_t base = (size_t)n * 256;
  h16[base + t] = (bf16_t)(emb[at * 128 + t] + fr);
  h16[base + 128 + t] = (bf16_t)(fp - fr);
}

// ---------------- fused edge embedding ----------------
__global__ __launch_bounds__(256) void k_edge_attr(
    const float* pos, const int* ei, const int* etr, const int* etp,
    const float* eeW1, const float* eeb1, const float* eeb2,
    const float* bemb, const float* ecb1, const float* ecb2,
    const bf16_t* WT, bf16_t* eattr, float* out) {
  __shared__ bf16_t buf0[64 * 256];
  __shared__ bf16_t buf1[64 * 256];
  const int tid = threadIdx.x, lane = tid & 63, wave = tid >> 6;
  const int l15 = lane & 15, quad = lane >> 4;
  const int eBase = blockIdx.x * 64;

  // phase 1: hidden = silu(d*W1 + b1) -> buf0; also emit d output
  {
    int r = tid >> 2, cb = (tid & 3) << 6;
    int e = eBase + r;
    int s = ei[e], dn = ei[EE + e];
    float d0 = pos[dn * 3 + 0] - pos[s * 3 + 0];
    float d1 = pos[dn * 3 + 1] - pos[s * 3 + 1];
    float d2 = pos[dn * 3 + 2] - pos[s * 3 + 2];
    float dd = sqrtf(d0 * d0 + d1 * d1 + d2 * d2);
    if ((tid & 3) == 0) out[3 * EE + e] = dd;
    for (int cc = 0; cc < 64; ++cc) {
      int c = cb + cc;
      buf0[swz(r, c)] = (bf16_t)silu_f(dd * eeW1[c] + eeb1[c]);
    }
  }
  __syncthreads();
  f32x4 acc[4][4];
  // GEMM1: mlp_d = hidden @ eeW2 (bias in gate epilogue)
  zacc(acc);
  gemm_lds<4, 4, 8>(buf0, WT + OFF_EEW2T, 256, wave * 64, acc, lane);
  __syncthreads();
  // gates: attr_r -> buf0, attr_p -> buf1
#pragma unroll
  for (int rt = 0; rt < 4; ++rt)
#pragma unroll
    for (int reg = 0; reg < 4; ++reg) {
      int r = rt * 16 + quad * 4 + reg, e = eBase + r;
      int tr = etr[e], tp = etp[e];
#pragma unroll
      for (int nt = 0; nt < 4; ++nt) {
        int c = wave * 64 + nt * 16 + l15;
        float mlp = acc[rt][nt][reg] + eeb2[c];
        buf0[swz(r, c)] = (bf16_t)(mlp * bemb[tr * 256 + c]);
        buf1[swz(r, c)] = (bf16_t)(mlp * bemb[tp * 256 + c]);
      }
    }
  __syncthreads();
  // GEMM2: s1 = silu(cat(attr_r, attr_p) @ ecW1 + b1)
  zacc(acc);
  gemm_lds<4, 4, 8>(buf0, WT + OFF_ECW1T, 512, wave * 64, acc, lane);
  gemm_lds<4, 4, 8>(buf1, WT + OFF_ECW1T + 256, 512, wave * 64, acc, lane);
  __syncthreads();
#pragma unroll
  for (int rt = 0; rt < 4; ++rt)
#pragma unroll
    for (int reg = 0; reg < 4; ++reg) {
      int r = rt * 16 + quad * 4 + reg;
#pragma unroll
      for (int nt = 0; nt < 4; ++nt) {
        int c = wave * 64 + nt * 16 + l15;
        buf0[swz(r, c)] = (bf16_t)silu_f(acc[rt][nt][reg] + ecb1[c]);
      }
    }
  __syncthreads();
  // GEMM3: edge_attr = s1 @ ecW2 + b2 -> global (de-swizzled direct store)
  zacc(acc);
  gemm_lds<4, 4, 8>(buf0, WT + OFF_ECW2T, 256, wave * 64, acc, lane);
#pragma unroll
  for (int rt = 0; rt < 4; ++rt)
#pragma unroll
    for (int reg = 0; reg < 4; ++reg) {
      int r = rt * 16 + quad * 4 + reg;
#pragma unroll
      for (int nt = 0; nt < 4; ++nt) {
        int c = wave * 64 + nt * 16 + l15;
        eattr[(size_t)(eBase + r) * 256 + c] = (bf16_t)(acc[rt][nt][reg] + ecb2[c]);
      }
    }
}

// ------- message + segment-sum: one block per (molecule, dst node) -------
// Edge structure (from reference): e = m*600 + i*24 + (j<i ? j : j-1), src=i, dst=j
__global__ __launch_bounds__(256) void k_msg(
    const bf16_t* __restrict__ eattr, const bf16_t* __restrict__ hl_g,
    const bf16_t* __restrict__ fW1T, const bf16_t* __restrict__ fW2T,
    const float* __restrict__ fb1, const float* __restrict__ fb2,
    bf16_t* __restrict__ agg) {
  __shared__ bf16_t buf[32 * 256];
  __shared__ bf16_t hlb[24 * 264];
  const int tid = threadIdx.x, lane = tid & 63, wave = tid >> 6;
  const int l15 = lane & 15, quad = lane >> 4;
  const int b = blockIdx.x, m = b / 25, j = b % 25;

  // stage the 24 in-edge eattr rows (pad to 32 with zeros)
  for (int task = tid; task < 32 * 32; task += 256) {
    int r = task >> 5, kc = task & 31;
    bf16x8 v;
    if (r < 24) {
      int i = r + (r >= j);
      int e = m * 600 + i * 24 + (r < j ? j - 1 : j);
      v = *(const bf16x8*)(eattr + (size_t)e * 256 + kc * 8);
    } else v = zero8();
    *(bf16x8*)(buf + r * 256 + ((kc ^ (r & 7)) << 3)) = v;
  }
  // stage hl rows for the 24 sources
  for (int task = tid; task < 24 * 32; task += 256) {
    int r = task >> 5, kc = task & 31;
    int i = r + (r >= j);
    *(bf16x8*)(hlb + r * 264 + kc * 8) =
        *(const bf16x8*)(hl_g + (size_t)(m * 25 + i) * 256 + kc * 8);
  }
  __syncthreads();
  f32x4 acc[2][4];
  zacc(acc);
  gemm_lds<2, 4, 8>(buf, fW1T, 256, wave * 64, acc, lane);
  __syncthreads();
#pragma unroll
  for (int rt = 0; rt < 2; ++rt)
#pragma unroll
    for (int reg = 0; reg < 4; ++reg) {
      int r = rt * 16 + quad * 4 + reg;
#pragma unroll
      for (int nt = 0; nt < 4; ++nt) {
        int c = wave * 64 + nt * 16 + l15;
        buf[swz(r, c)] = (bf16_t)ssp_f(acc[rt][nt][reg] + fb1[c]);
      }
    }
  __syncthreads();
  zacc(acc);
  gemm_lds<2, 4, 8>(buf, fW2T, 256, wave * 64, acc, lane);
  // multiply by hl[src] and reduce over the 24 rows -> agg[dst]
#pragma unroll
  for (int nt = 0; nt < 4; ++nt) {
    int c = wave * 64 + nt * 16 + l15;
    float fb2c = fb2[c];
    float vsum = 0.f;
#pragma unroll
    for (int rt = 0; rt < 2; ++rt)
#pragma unroll
      for (int reg = 0; reg < 4; ++reg) {
        int r = rt * 16 + quad * 4 + reg;
        if (r < 24)
          vsum += (acc[rt][nt][reg] + fb2c) * (float)hlb[r * 264 + c];
      }
    vsum += __shfl_xor(vsum, 16);
    vsum += __shfl_xor(vsum, 32);
    if (quad == 0) agg[(size_t)b * 256 + c] = (bf16_t)vsum;
  }
}

// ---------------- h += ssp(agg @ lin2 + b) ----------------
__global__ __launch_bounds__(256) void k_upd(
    const bf16_t* __restrict__ agg, const bf16_t* __restrict__ lin2T,
    const float* __restrict__ lin2b, bf16_t* h16) {
  __shared__ bf16_t buf[64 * 256];
  const int tid = threadIdx.x, lane = tid & 63, wave = tid >> 6;
  const int l15 = lane & 15, quad = lane >> 4;
  const int row0 = blockIdx.x * 64, colBase = blockIdx.y * 128 + wave * 32;
  for (int task = tid; task < 64 * 32; task += 256) {
    int r = task >> 5, kc = task & 31;
    int node = row0 + r;
    bf16x8 v = (node < NN) ? *(const bf16x8*)(agg + (size_t)node * 256 + kc * 8) : zero8();
    *(bf16x8*)(buf + r * 256 + ((kc ^ (r & 7)) << 3)) = v;
  }
  __syncthreads();
  f32x4 acc[4][2];
  zacc(acc);
  gemm_lds<4, 2, 8>(buf, lin2T, 256, colBase, acc, lane);
#pragma unroll
  for (int rt = 0; rt < 4; ++rt)
#pragma unroll
    for (int reg = 0; reg < 4; ++reg) {
      int r = rt * 16 + quad * 4 + reg, node = row0 + r;
      if (node < NN) {
#pragma unroll
        for (int nt = 0; nt < 2; ++nt) {
          int c = colBase + nt * 16 + l15;
          size_t idx = (size_t)node * 256 + c;
          h16[idx] = (bf16_t)((float)h16[idx] + ssp_f(acc[rt][nt][reg] + lin2b[c]));
        }
      }
    }
}

// ---------------- hl = h @ lin1 (no bias) ----------------
__global__ __launch_bounds__(256) void k_lin1(
    const bf16_t* __restrict__ h16, const bf16_t* __restrict__ lin1T,
    bf16_t* __restrict__ hl) {
  __shared__ bf16_t buf[64 * 256];
  const int tid = threadIdx.x, lane = tid & 63, wave = tid >> 6;
  const int l15 = lane & 15, quad = lane >> 4;
  const int row0 = blockIdx.x * 64, colBase = blockIdx.y * 128 + wave * 32;
  for (int task = tid; task < 64 * 32; task += 256) {
    int r = task >> 5, kc = task & 31;
    int node = row0 + r;
    bf16x8 v = (node < NN) ? *(const bf16x8*)(h16 + (size_t)node * 256 + kc * 8) : zero8();
    *(bf16x8*)(buf + r * 256 + ((kc ^ (r & 7)) << 3)) = v;
  }
  __syncthreads();
  f32x4 acc[4][2];
  zacc(acc);
  gemm_lds<4, 2, 8>(buf, lin1T, 256, colBase, acc, lane);
#pragma unroll
  for (int rt = 0; rt < 4; ++rt)
#pragma unroll
    for (int reg = 0; reg < 4; ++reg) {
      int r = rt * 16 + quad * 4 + reg, node = row0 + r;
      if (node < NN) {
#pragma unroll
        for (int nt = 0; nt < 2; ++nt) {
          int c = colBase + nt * 16 + l15;
          hl[(size_t)node * 256 + c] = (bf16_t)acc[rt][nt][reg];
        }
      }
    }
}

// ---------------- output head ----------------
__global__ __launch_bounds__(256) void k_head(
    const bf16_t* __restrict__ h16, const bf16_t* __restrict__ eattr, const int* ei,
    const float* gb1, const float* gb2, const float* gW3, const float* gb3,
    const bf16_t* WT, float* out) {
  __shared__ bf16_t buf0[64 * 256];
  __shared__ bf16_t buf1[64 * 256];
  const int tid = threadIdx.x, lane = tid & 63, wave = tid >> 6;
  const int l15 = lane & 15, quad = lane >> 4;
  const int eBase = blockIdx.x * 64;

  // stage h[src]*h[dst] -> buf0
  for (int task = tid; task < 64 * 32; task += 256) {
    int r = task >> 5, kc = task & 31;
    int e = eBase + r, s = ei[e], dn = ei[EE + e];
    bf16x8 a = *(const bf16x8*)(h16 + (size_t)s * 256 + kc * 8);
    bf16x8 b = *(const bf16x8*)(h16 + (size_t)dn * 256 + kc * 8);
    bf16x8 v;
#pragma unroll
    for (int q = 0; q < 8; ++q) v[q] = (bf16_t)((float)a[q] * (float)b[q]);
    *(bf16x8*)(buf0 + r * 256 + ((kc ^ (r & 7)) << 3)) = v;
  }
  // stage edge_attr -> buf1
  for (int task = tid; task < 64 * 32; task += 256) {
    int r = task >> 5, kc = task & 31;
    *(bf16x8*)(buf1 + r * 256 + ((kc ^ (r & 7)) << 3)) =
        *(const bf16x8*)(eattr + (size_t)(eBase + r) * 256 + kc * 8);
  }
  // emit edge_index outputs (f32)
  if (tid < 64) {
    int e = eBase + tid;
    out[EE + e] = (float)ei[e];
    out[2 * EE + e] = (float)ei[EE + e];
  }
  __syncthreads();
  f32x4 acc[4][4];
  zacc(acc);
  gemm_lds<4, 4, 8>(buf0, WT + OFF_GW1T, 512, wave * 64, acc, lane);
  gemm_lds<4, 4, 8>(buf1, WT + OFF_GW1T + 256, 512, wave * 64, acc, lane);
  __syncthreads();
#pragma unroll
  for (int rt = 0; rt < 4; ++rt)
#pragma unroll
    for (int reg = 0; reg < 4; ++reg) {
      int r = rt * 16 + quad * 4 + reg;
#pragma unroll
      for (int nt = 0; nt < 4; ++nt) {
        int c = wave * 64 + nt * 16 + l15;
        buf0[swz(r, c)] = (bf16_t)silu_f(acc[rt][nt][reg] + gb1[c]);
      }
    }
  __syncthreads();
  f32x4 acc2[4][2];
  zacc(acc2);
  gemm_lds<4, 2, 8>(buf0, WT + OFF_GW2T, 256, wave * 32, acc2, lane);
  __syncthreads();
#pragma unroll
  for (int rt = 0; rt < 4; ++rt)
#pragma unroll
    for (int reg = 0; reg < 4; ++reg) {
      int r = rt * 16 + quad * 4 + reg;
#pragma unroll
      for (int nt = 0; nt < 2; ++nt) {
        int c = wave * 32 + nt * 16 + l15;
        buf1[swz(r, c)] = (bf16_t)silu_f(acc2[rt][nt][reg] + gb2[c]);
      }
    }
  __syncthreads();
  if (tid < 64) {
    float s = gb3[0];
    for (int c = 0; c < 128; ++c)
      s += (float)buf1[swz(tid, c)] * gW3[c];
    out[eBase + tid] = s;
  }
}

extern "C" void kernel_launch(void* const* d_in, const int* in_sizes, int n_in,
                              void* d_out, int out_size, void* d_ws, size_t ws_size,
                              hipStream_t stream) {
  const float* pos   = (const float*)d_in[0];
  const float* rfeat = (const float*)d_in[1];
  const float* pfeat = (const float*)d_in[2];
  const float* emb   = (const float*)d_in[3];
  const float* Wf    = (const float*)d_in[4];
  const float* bemb  = (const float*)d_in[5];
  const float* eeW1  = (const float*)d_in[6];
  const float* eeb1  = (const float*)d_in[7];
  const float* eeW2  = (const float*)d_in[8];
  const float* eeb2  = (const float*)d_in[9];
  const float* ecW1  = (const float*)d_in[10];
  const float* ecb1  = (const float*)d_in[11];
  const float* ecW2  = (const float*)d_in[12];
  const float* ecb2  = (const float*)d_in[13];
  const float* fW1   = (const float*)d_in[14];
  const float* fb1   = (const float*)d_in[15];
  const float* fW2   = (const float*)d_in[16];
  const float* fb2   = (const float*)d_in[17];
  const float* ln1   = (const float*)d_in[18];
  const float* ln2   = (const float*)d_in[19];
  const float* ln2b  = (const float*)d_in[20];
  const float* gW1   = (const float*)d_in[21];
  const float* gb1   = (const float*)d_in[22];
  const float* gW2   = (const float*)d_in[23];
  const float* gb2   = (const float*)d_in[24];
  const float* gW3   = (const float*)d_in[25];
  const float* gb3   = (const float*)d_in[26];
  const int* atype = (const int*)d_in[27];
  const int* ei    = (const int*)d_in[28];
  const int* etr   = (const int*)d_in[29];
  const int* etp   = (const int*)d_in[30];

  float* out = (float*)d_out;
  char* ws = (char*)d_ws;
  bf16_t* WT    = (bf16_t*)(ws);
  bf16_t* h16   = (bf16_t*)(ws + WSOFF_H16);
  bf16_t* hl    = (bf16_t*)(ws + WSOFF_HL);
  bf16_t* agg   = (bf16_t*)(ws + WSOFF_AGG);
  bf16_t* eattr = (bf16_t*)(ws + WSOFF_EATTR);

  k_transpose<<<dim3(512, 21), 256, 0, stream>>>(eeW2, ecW1, ecW2, fW1, fW2, ln1, ln2, gW1, gW2, WT);
  k_node<<<NN, 128, 0, stream>>>(rfeat, pfeat, emb, Wf, atype, h16);
  k_edge_attr<<<EE / 64, 256, 0, stream>>>(pos, ei, etr, etp, eeW1, eeb1, eeb2,
                                           bemb, ecb1, ecb2, WT, eattr, out);
  k_lin1<<<dim3(79, 2), 256, 0, stream>>>(h16, WT + OFF_LN1T, hl);
  for (int l = 0; l < 4; ++l) {
    k_msg<<<NN, 256, 0, stream>>>(eattr, hl,
                                  WT + OFF_FW1T + l * 65536, WT + OFF_FW2T + l * 65536,
                                  fb1 + l * 256, fb2 + l * 256, agg);
    k_upd<<<dim3(79, 2), 256, 0, stream>>>(agg, WT + OFF_LN2T + l * 65536,
                                           ln2b + l * 256, h16);
    if (l < 3)
      k_lin1<<<dim3(79, 2), 256, 0, stream>>>(h16, WT + OFF_LN1T + (l + 1) * 65536, hl);
  }
  k_head<<<EE / 64, 256, 0, stream>>>(h16, eattr, ei, gb1, gb2, gW3, gb3, WT, out);
}

// Round 6
// 1105.312 us; speedup vs baseline: 2.7727x; 1.2852x over previous
//
#include <hip/hip_runtime.h>

#define NN 5000
#define EE 120000

typedef __bf16 bf16_t;
typedef __bf16 bf16x8 __attribute__((ext_vector_type(8)));
typedef float f32x4 __attribute__((ext_vector_type(4)));

// W^T offsets (elements) inside ws
#define OFF_EEW2T 0
#define OFF_ECW1T 65536
#define OFF_ECW2T 196608
#define OFF_FW1T  262144
#define OFF_FW2T  524288
#define OFF_LN1T  786432
#define OFF_LN2T  1048576
#define OFF_GW1T  1310720
#define OFF_GW2T  1441792

// ws byte offsets (total 72,069,120 B — proven available)
#define WSOFF_H16   2949120
#define WSOFF_HL    5509120
#define WSOFF_AGG   8069120
#define WSOFF_EATTR 10629120

// XOR-swizzled [rows x 256] bf16 tile: 16B chunks permuted by row, conflict-free
__device__ __forceinline__ int swz(int r, int c) {
  return r * 256 + ((((c >> 3) ^ (r & 7)) << 3) | (c & 7));
}

__device__ __forceinline__ float silu_f(float x) { return x / (1.f + __expf(-x)); }
// fast shifted-softplus: native v_exp/v_log; |x| is O(1) here (no overflow path)
__device__ __forceinline__ float ssp_f(float x) {
  return __logf(1.f + __expf(x)) - 0.6931472f;
}

__device__ __forceinline__ bf16x8 zero8() {
  bf16x8 v;
#pragma unroll
  for (int q = 0; q < 8; ++q) v[q] = (__bf16)0.f;
  return v;
}

template<int RT, int NT>
__device__ __forceinline__ void zacc(f32x4 (&acc)[RT][NT]) {
#pragma unroll
  for (int i = 0; i < RT; ++i)
#pragma unroll
    for (int j = 0; j < NT; ++j) {
      f32x4 z = {0.f, 0.f, 0.f, 0.f};
      acc[i][j] = z;
    }
}

// A: LDS swizzled tile, rows rt*16+l15, k chunks ks*32+quad*8
// WT: global W^T [N, ldK] row-major (bf16); effective B[k][n] = WT[n*ldK + k]
template<int RT, int NT, int KS>
__device__ __forceinline__ void gemm_lds(const bf16_t* __restrict__ A,
                                         const bf16_t* __restrict__ WT, int ldK,
                                         int colBase, f32x4 (&acc)[RT][NT], int lane) {
  const int l15 = lane & 15, quad = lane >> 4;
#pragma unroll
  for (int ks = 0; ks < KS; ++ks) {
    const int kc = ks * 4 + quad;
    bf16x8 a[RT];
#pragma unroll
    for (int rt = 0; rt < RT; ++rt) {
      int r = rt * 16 + l15;
      a[rt] = *(const bf16x8*)(A + r * 256 + ((kc ^ (r & 7)) << 3));
    }
#pragma unroll
    for (int nt = 0; nt < NT; ++nt) {
      const bf16x8 b = *(const bf16x8*)(WT + (size_t)(colBase + nt * 16 + l15) * ldK + kc * 8);
#pragma unroll
      for (int rt = 0; rt < RT; ++rt)
        acc[rt][nt] = __builtin_amdgcn_mfma_f32_16x16x32_bf16(a[rt], b, acc[rt][nt], 0, 0, 0);
    }
  }
}

// ---------------- weight transpose (f32 -> bf16 W^T) ----------------
__global__ __launch_bounds__(256) void k_transpose(
    const float* eeW2, const float* ecW1, const float* ecW2,
    const float* fW1, const float* fW2, const float* ln1, const float* ln2,
    const float* gW1, const float* gW2, bf16_t* WT) {
  int seg = blockIdx.y;
  const float* src; int K, Nn, off;
  if (seg == 0)       { src = eeW2; K = 256; Nn = 256; off = OFF_EEW2T; }
  else if (seg == 1)  { src = ecW1; K = 512; Nn = 256; off = OFF_ECW1T; }
  else if (seg == 2)  { src = ecW2; K = 256; Nn = 256; off = OFF_ECW2T; }
  else if (seg <= 6)  { int l = seg - 3;  src = fW1 + l * 65536; K = 256; Nn = 256; off = OFF_FW1T + l * 65536; }
  else if (seg <= 10) { int l = seg - 7;  src = fW2 + l * 65536; K = 256; Nn = 256; off = OFF_FW2T + l * 65536; }
  else if (seg <= 14) { int l = seg - 11; src = ln1 + l * 65536; K = 256; Nn = 256; off = OFF_LN1T + l * 65536; }
  else if (seg <= 18) { int l = seg - 15; src = ln2 + l * 65536; K = 256; Nn = 256; off = OFF_LN2T + l * 65536; }
  else if (seg == 19) { src = gW1; K = 512; Nn = 256; off = OFF_GW1T; }
  else                { src = gW2; K = 256; Nn = 128; off = OFF_GW2T; }
  int idx = blockIdx.x * 256 + threadIdx.x;
  if (idx >= K * Nn) return;
  int sh = (K == 512) ? 9 : 8;
  int k = idx & (K - 1), n = idx >> sh;
  WT[off + idx] = (bf16_t)src[k * Nn + n];
}

// ---------------- node embedding ----------------
__global__ __launch_bounds__(128) void k_node(
    const float* r_feat, const float* p_feat, const float* emb, const float* Wf,
    const int* atype, bf16_t* h16) {
  __shared__ float rf[27], pf[27];
  int n = blockIdx.x, t = threadIdx.x;
  if (t < 27) { rf[t] = r_feat[n * 27 + t]; pf[t] = p_feat[n * 27 + t]; }
  __syncthreads();
  float fr = 0.f, fp = 0.f;
#pragma unroll
  for (int k = 0; k < 27; ++k) {
    float w = Wf[k * 128 + t];
    fr += rf[k] * w; fp += pf[k] * w;
  }
  int at = atype[n];
  size_t base = (size_t)n * 256;
  h16[base + t] = (bf16_t)(emb[at * 128 + t] + fr);
  h16[base + 128 + t] = (bf16_t)(fp - fr);
}

// ---------------- fused edge embedding ----------------
__global__ __launch_bounds__(256) void k_edge_attr(
    const float* pos, const int* ei, const int* etr, const int* etp,
    const float* eeW1, const float* eeb1, const float* eeb2,
    const float* bemb, const float* ecb1, const float* ecb2,
    const bf16_t* WT, bf16_t* eattr, float* out) {
  __shared__ bf16_t buf0[64 * 256];
  __shared__ bf16_t buf1[64 * 256];
  const int tid = threadIdx.x, lane = tid & 63, wave = tid >> 6;
  const int l15 = lane & 15, quad = lane >> 4;
  const int eBase = blockIdx.x * 64;

  // phase 1: hidden = silu(d*W1 + b1) -> buf0 (vectorized b128 stores); emit d
  {
    int r = tid >> 2, cb = (tid & 3) << 6;
    int e = eBase + r;
    int s = ei[e], dn = ei[EE + e];
    float d0 = pos[dn * 3 + 0] - pos[s * 3 + 0];
    float d1 = pos[dn * 3 + 1] - pos[s * 3 + 1];
    float d2 = pos[dn * 3 + 2] - pos[s * 3 + 2];
    float dd = sqrtf(d0 * d0 + d1 * d1 + d2 * d2);
    if ((tid & 3) == 0) out[3 * EE + e] = dd;
#pragma unroll
    for (int g = 0; g < 8; ++g) {
      int c0 = cb + g * 8;
      bf16x8 v;
#pragma unroll
      for (int q = 0; q < 8; ++q)
        v[q] = (bf16_t)silu_f(dd * eeW1[c0 + q] + eeb1[c0 + q]);
      *(bf16x8*)(buf0 + swz(r, c0)) = v;
    }
  }
  __syncthreads();
  f32x4 acc[4][4];
  // GEMM1: mlp_d = hidden @ eeW2 (bias in gate epilogue)
  zacc(acc);
  gemm_lds<4, 4, 8>(buf0, WT + OFF_EEW2T, 256, wave * 64, acc, lane);
  __syncthreads();
  // gates: attr_r -> buf0, attr_p -> buf1
#pragma unroll
  for (int rt = 0; rt < 4; ++rt)
#pragma unroll
    for (int reg = 0; reg < 4; ++reg) {
      int r = rt * 16 + quad * 4 + reg, e = eBase + r;
      int tr = etr[e], tp = etp[e];
#pragma unroll
      for (int nt = 0; nt < 4; ++nt) {
        int c = wave * 64 + nt * 16 + l15;
        float mlp = acc[rt][nt][reg] + eeb2[c];
        buf0[swz(r, c)] = (bf16_t)(mlp * bemb[tr * 256 + c]);
        buf1[swz(r, c)] = (bf16_t)(mlp * bemb[tp * 256 + c]);
      }
    }
  __syncthreads();
  // GEMM2: s1 = silu(cat(attr_r, attr_p) @ ecW1 + b1)
  zacc(acc);
  gemm_lds<4, 4, 8>(buf0, WT + OFF_ECW1T, 512, wave * 64, acc, lane);
  gemm_lds<4, 4, 8>(buf1, WT + OFF_ECW1T + 256, 512, wave * 64, acc, lane);
  __syncthreads();
#pragma unroll
  for (int rt = 0; rt < 4; ++rt)
#pragma unroll
    for (int reg = 0; reg < 4; ++reg) {
      int r = rt * 16 + quad * 4 + reg;
#pragma unroll
      for (int nt = 0; nt < 4; ++nt) {
        int c = wave * 64 + nt * 16 + l15;
        buf0[swz(r, c)] = (bf16_t)silu_f(acc[rt][nt][reg] + ecb1[c]);
      }
    }
  __syncthreads();
  // GEMM3: edge_attr = s1 @ ecW2 + b2 -> global (coalesced direct store)
  zacc(acc);
  gemm_lds<4, 4, 8>(buf0, WT + OFF_ECW2T, 256, wave * 64, acc, lane);
#pragma unroll
  for (int rt = 0; rt < 4; ++rt)
#pragma unroll
    for (int reg = 0; reg < 4; ++reg) {
      int r = rt * 16 + quad * 4 + reg;
#pragma unroll
      for (int nt = 0; nt < 4; ++nt) {
        int c = wave * 64 + nt * 16 + l15;
        eattr[(size_t)(eBase + r) * 256 + c] = (bf16_t)(acc[rt][nt][reg] + ecb2[c]);
      }
    }
}

// ------- message + segment-sum: one block per (molecule, dst node) -------
// Edge structure (from reference): e = m*600 + i*24 + (j<i ? j : j-1), src=i, dst=j
__global__ __launch_bounds__(256) void k_msg(
    const bf16_t* __restrict__ eattr, const bf16_t* __restrict__ hl_g,
    const bf16_t* __restrict__ fW1T, const bf16_t* __restrict__ fW2T,
    const float* __restrict__ fb1, const float* __restrict__ fb2,
    bf16_t* __restrict__ agg) {
  __shared__ bf16_t buf[32 * 256];
  __shared__ bf16_t hlb[24 * 264];
  const int tid = threadIdx.x, lane = tid & 63, wave = tid >> 6;
  const int l15 = lane & 15, quad = lane >> 4;
  const int b = blockIdx.x, m = b / 25, j = b % 25;

  // stage the 24 in-edge eattr rows (pad rows 24..31 with zeros)
  for (int task = tid; task < 32 * 32; task += 256) {
    int r = task >> 5, kc = task & 31;
    bf16x8 v;
    if (r < 24) {
      int i = r + (r >= j);
      int e = m * 600 + i * 24 + (r < j ? j - 1 : j);
      v = *(const bf16x8*)(eattr + (size_t)e * 256 + kc * 8);
    } else v = zero8();
    *(bf16x8*)(buf + r * 256 + ((kc ^ (r & 7)) << 3)) = v;
  }
  // stage hl rows for the 24 sources
  for (int task = tid; task < 24 * 32; task += 256) {
    int r = task >> 5, kc = task & 31;
    int i = r + (r >= j);
    *(bf16x8*)(hlb + r * 264 + kc * 8) =
        *(const bf16x8*)(hl_g + (size_t)(m * 25 + i) * 256 + kc * 8);
  }
  __syncthreads();
  f32x4 acc[2][4];
  zacc(acc);
  gemm_lds<2, 4, 8>(buf, fW1T, 256, wave * 64, acc, lane);
  __syncthreads();
  // epilogue 1: only the 24 valid rows (pad rows keep their staged zeros)
  {
    float b1[4];
#pragma unroll
    for (int nt = 0; nt < 4; ++nt) b1[nt] = fb1[wave * 64 + nt * 16 + l15];
#pragma unroll
    for (int rt = 0; rt < 2; ++rt)
#pragma unroll
      for (int reg = 0; reg < 4; ++reg) {
        int r = rt * 16 + quad * 4 + reg;
        if (r < 24) {
#pragma unroll
          for (int nt = 0; nt < 4; ++nt) {
            int c = wave * 64 + nt * 16 + l15;
            buf[swz(r, c)] = (bf16_t)ssp_f(acc[rt][nt][reg] + b1[nt]);
          }
        }
      }
  }
  __syncthreads();
  zacc(acc);
  gemm_lds<2, 4, 8>(buf, fW2T, 256, wave * 64, acc, lane);
  // multiply by hl[src] and reduce over the 24 rows -> agg[dst]
#pragma unroll
  for (int nt = 0; nt < 4; ++nt) {
    int c = wave * 64 + nt * 16 + l15;
    float fb2c = fb2[c];
    float vsum = 0.f;
#pragma unroll
    for (int rt = 0; rt < 2; ++rt)
#pragma unroll
      for (int reg = 0; reg < 4; ++reg) {
        int r = rt * 16 + quad * 4 + reg;
        if (r < 24)
          vsum += (acc[rt][nt][reg] + fb2c) * (float)hlb[r * 264 + c];
      }
    vsum += __shfl_xor(vsum, 16);
    vsum += __shfl_xor(vsum, 32);
    if (quad == 0) agg[(size_t)b * 256 + c] = (bf16_t)vsum;
  }
}

// -------- fused: h += ssp(agg @ lin2 + b); optionally hl = h @ lin1 --------
__global__ __launch_bounds__(256) void k_updlin(
    const bf16_t* __restrict__ agg, const bf16_t* __restrict__ lin2T,
    const float* __restrict__ lin2b, bf16_t* h16,
    const bf16_t* __restrict__ lin1T, bf16_t* __restrict__ hl, int do_lin1) {
  __shared__ bf16_t buf[32 * 256];
  __shared__ bf16_t hbuf[32 * 256];
  const int tid = threadIdx.x, lane = tid & 63, wave = tid >> 6;
  const int l15 = lane & 15, quad = lane >> 4;
  const int row0 = blockIdx.x * 32;
  // stage agg tile + old h tile
  for (int task = tid; task < 32 * 32; task += 256) {
    int r = task >> 5, kc = task & 31;
    int node = row0 + r;
    bf16x8 va = (node < NN) ? *(const bf16x8*)(agg + (size_t)node * 256 + kc * 8) : zero8();
    bf16x8 vh = (node < NN) ? *(const bf16x8*)(h16 + (size_t)node * 256 + kc * 8) : zero8();
    *(bf16x8*)(buf + r * 256 + ((kc ^ (r & 7)) << 3)) = va;
    *(bf16x8*)(hbuf + r * 256 + ((kc ^ (r & 7)) << 3)) = vh;
  }
  __syncthreads();
  f32x4 acc[2][4];
  zacc(acc);
  gemm_lds<2, 4, 8>(buf, lin2T, 256, wave * 64, acc, lane);
  // epilogue: h_new = h_old + ssp(acc + b) -> hbuf (LDS) + h16 (global)
  {
    float b2[4];
#pragma unroll
    for (int nt = 0; nt < 4; ++nt) b2[nt] = lin2b[wave * 64 + nt * 16 + l15];
#pragma unroll
    for (int rt = 0; rt < 2; ++rt)
#pragma unroll
      for (int reg = 0; reg < 4; ++reg) {
        int r = rt * 16 + quad * 4 + reg, node = row0 + r;
#pragma unroll
        for (int nt = 0; nt < 4; ++nt) {
          int c = wave * 64 + nt * 16 + l15;
          int idx = swz(r, c);
          float hn = (float)hbuf[idx] + ssp_f(acc[rt][nt][reg] + b2[nt]);
          bf16_t hb = (bf16_t)hn;
          hbuf[idx] = hb;
          if (node < NN) h16[(size_t)node * 256 + c] = hb;
        }
      }
  }
  if (!do_lin1) return;
  __syncthreads();
  f32x4 acc2[2][4];
  zacc(acc2);
  gemm_lds<2, 4, 8>(hbuf, lin1T, 256, wave * 64, acc2, lane);
#pragma unroll
  for (int rt = 0; rt < 2; ++rt)
#pragma unroll
    for (int reg = 0; reg < 4; ++reg) {
      int r = rt * 16 + quad * 4 + reg, node = row0 + r;
      if (node < NN) {
#pragma unroll
        for (int nt = 0; nt < 4; ++nt) {
          int c = wave * 64 + nt * 16 + l15;
          hl[(size_t)node * 256 + c] = (bf16_t)acc2[rt][nt][reg];
        }
      }
    }
}

// ---------------- hl = h @ lin1 (no bias), initial ----------------
__global__ __launch_bounds__(256) void k_lin1(
    const bf16_t* __restrict__ h16, const bf16_t* __restrict__ lin1T,
    bf16_t* __restrict__ hl) {
  __shared__ bf16_t buf[32 * 256];
  const int tid = threadIdx.x, lane = tid & 63, wave = tid >> 6;
  const int l15 = lane & 15, quad = lane >> 4;
  const int row0 = blockIdx.x * 32;
  for (int task = tid; task < 32 * 32; task += 256) {
    int r = task >> 5, kc = task & 31;
    int node = row0 + r;
    bf16x8 v = (node < NN) ? *(const bf16x8*)(h16 + (size_t)node * 256 + kc * 8) : zero8();
    *(bf16x8*)(buf + r * 256 + ((kc ^ (r & 7)) << 3)) = v;
  }
  __syncthreads();
  f32x4 acc[2][4];
  zacc(acc);
  gemm_lds<2, 4, 8>(buf, lin1T, 256, wave * 64, acc, lane);
#pragma unroll
  for (int rt = 0; rt < 2; ++rt)
#pragma unroll
    for (int reg = 0; reg < 4; ++reg) {
      int r = rt * 16 + quad * 4 + reg, node = row0 + r;
      if (node < NN) {
#pragma unroll
        for (int nt = 0; nt < 4; ++nt) {
          int c = wave * 64 + nt * 16 + l15;
          hl[(size_t)node * 256 + c] = (bf16_t)acc[rt][nt][reg];
        }
      }
    }
}

// ---------------- output head ----------------
__global__ __launch_bounds__(256) void k_head(
    const bf16_t* __restrict__ h16, const bf16_t* __restrict__ eattr, const int* ei,
    const float* gb1, const float* gb2, const float* gW3, const float* gb3,
    const bf16_t* WT, float* out) {
  __shared__ bf16_t buf0[64 * 256];
  __shared__ bf16_t buf1[64 * 256];
  const int tid = threadIdx.x, lane = tid & 63, wave = tid >> 6;
  const int l15 = lane & 15, quad = lane >> 4;
  const int eBase = blockIdx.x * 64;

  // stage h[src]*h[dst] -> buf0
  for (int task = tid; task < 64 * 32; task += 256) {
    int r = task >> 5, kc = task & 31;
    int e = eBase + r, s = ei[e], dn = ei[EE + e];
    bf16x8 a = *(const bf16x8*)(h16 + (size_t)s * 256 + kc * 8);
    bf16x8 b = *(const bf16x8*)(h16 + (size_t)dn * 256 + kc * 8);
    bf16x8 v;
#pragma unroll
    for (int q = 0; q < 8; ++q) v[q] = (bf16_t)((float)a[q] * (float)b[q]);
    *(bf16x8*)(buf0 + r * 256 + ((kc ^ (r & 7)) << 3)) = v;
  }
  // stage edge_attr -> buf1
  for (int task = tid; task < 64 * 32; task += 256) {
    int r = task >> 5, kc = task & 31;
    *(bf16x8*)(buf1 + r * 256 + ((kc ^ (r & 7)) << 3)) =
        *(const bf16x8*)(eattr + (size_t)(eBase + r) * 256 + kc * 8);
  }
  // emit edge_index outputs (f32)
  if (tid < 128) {
    int e = eBase + (tid & 63);
    int half = tid >> 6;
    out[EE + half * EE + e] = (float)ei[half * EE + e];
  }
  __syncthreads();
  f32x4 acc[4][4];
  zacc(acc);
  gemm_lds<4, 4, 8>(buf0, WT + OFF_GW1T, 512, wave * 64, acc, lane);
  gemm_lds<4, 4, 8>(buf1, WT + OFF_GW1T + 256, 512, wave * 64, acc, lane);
  __syncthreads();
#pragma unroll
  for (int rt = 0; rt < 4; ++rt)
#pragma unroll
    for (int reg = 0; reg < 4; ++reg) {
      int r = rt * 16 + quad * 4 + reg;
#pragma unroll
      for (int nt = 0; nt < 4; ++nt) {
        int c = wave * 64 + nt * 16 + l15;
        buf0[swz(r, c)] = (bf16_t)silu_f(acc[rt][nt][reg] + gb1[c]);
      }
    }
  __syncthreads();
  f32x4 acc2[4][2];
  zacc(acc2);
  gemm_lds<4, 2, 8>(buf0, WT + OFF_GW2T, 256, wave * 32, acc2, lane);
  __syncthreads();
#pragma unroll
  for (int rt = 0; rt < 4; ++rt)
#pragma unroll
    for (int reg = 0; reg < 4; ++reg) {
      int r = rt * 16 + quad * 4 + reg;
#pragma unroll
      for (int nt = 0; nt < 2; ++nt) {
        int c = wave * 32 + nt * 16 + l15;
        buf1[swz(r, c)] = (bf16_t)silu_f(acc2[rt][nt][reg] + gb2[c]);
      }
    }
  __syncthreads();
  // final dot: 4 lanes per edge, 32 cols each, shfl-reduce
  {
    int r = tid >> 2, part = tid & 3;
    float s = 0.f;
#pragma unroll
    for (int cc = 0; cc < 32; ++cc) {
      int c = part * 32 + cc;
      s += (float)buf1[swz(r, c)] * gW3[c];
    }
    s += __shfl_xor(s, 1);
    s += __shfl_xor(s, 2);
    if (part == 0) out[eBase + r] = s + gb3[0];
  }
}

extern "C" void kernel_launch(void* const* d_in, const int* in_sizes, int n_in,
                              void* d_out, int out_size, void* d_ws, size_t ws_size,
                              hipStream_t stream) {
  const float* pos   = (const float*)d_in[0];
  const float* rfeat = (const float*)d_in[1];
  const float* pfeat = (const float*)d_in[2];
  const float* emb   = (const float*)d_in[3];
  const float* Wf    = (const float*)d_in[4];
  const float* bemb  = (const float*)d_in[5];
  const float* eeW1  = (const float*)d_in[6];
  const float* eeb1  = (const float*)d_in[7];
  const float* eeW2  = (const float*)d_in[8];
  const float* eeb2  = (const float*)d_in[9];
  const float* ecW1  = (const float*)d_in[10];
  const float* ecb1  = (const float*)d_in[11];
  const float* ecW2  = (const float*)d_in[12];
  const float* ecb2  = (const float*)d_in[13];
  const float* fW1   = (const float*)d_in[14];
  const float* fb1   = (const float*)d_in[15];
  const float* fW2   = (const float*)d_in[16];
  const float* fb2   = (const float*)d_in[17];
  const float* ln1   = (const float*)d_in[18];
  const float* ln2   = (const float*)d_in[19];
  const float* ln2b  = (const float*)d_in[20];
  const float* gW1   = (const float*)d_in[21];
  const float* gb1   = (const float*)d_in[22];
  const float* gW2   = (const float*)d_in[23];
  const float* gb2   = (const float*)d_in[24];
  const float* gW3   = (const float*)d_in[25];
  const float* gb3   = (const float*)d_in[26];
  const int* atype = (const int*)d_in[27];
  const int* ei    = (const int*)d_in[28];
  const int* etr   = (const int*)d_in[29];
  const int* etp   = (const int*)d_in[30];

  float* out = (float*)d_out;
  char* ws = (char*)d_ws;
  bf16_t* WT    = (bf16_t*)(ws);
  bf16_t* h16   = (bf16_t*)(ws + WSOFF_H16);
  bf16_t* hl    = (bf16_t*)(ws + WSOFF_HL);
  bf16_t* agg   = (bf16_t*)(ws + WSOFF_AGG);
  bf16_t* eattr = (bf16_t*)(ws + WSOFF_EATTR);

  k_transpose<<<dim3(512, 21), 256, 0, stream>>>(eeW2, ecW1, ecW2, fW1, fW2, ln1, ln2, gW1, gW2, WT);
  k_node<<<NN, 128, 0, stream>>>(rfeat, pfeat, emb, Wf, atype, h16);
  k_edge_attr<<<EE / 64, 256, 0, stream>>>(pos, ei, etr, etp, eeW1, eeb1, eeb2,
                                           bemb, ecb1, ecb2, WT, eattr, out);
  k_lin1<<<157, 256, 0, stream>>>(h16, WT + OFF_LN1T, hl);
  for (int l = 0; l < 4; ++l) {
    k_msg<<<NN, 256, 0, stream>>>(eattr, hl,
                                  WT + OFF_FW1T + l * 65536, WT + OFF_FW2T + l * 65536,
                                  fb1 + l * 256, fb2 + l * 256, agg);
    k_updlin<<<157, 256, 0, stream>>>(agg, WT + OFF_LN2T + l * 65536, ln2b + l * 256,
                                      h16, WT + OFF_LN1T + (l + 1 < 4 ? l + 1 : 0) * 65536,
                                      hl, l < 3 ? 1 : 0);
  }
  k_head<<<EE / 64, 256, 0, stream>>>(h16, eattr, ei, gb1, gb2, gW3, gb3, WT, out);
}